// Round 12
// baseline (867.993 us; speedup 1.0000x reference)
//
#include <hip/hip_runtime.h>

#define B_SZ 4
#define T_SZ 2048
#define D_SZ 1024
#define H_SZ 16
#define DK_SZ 64
#define M_SZ (B_SZ * T_SZ)  // 8192

typedef __attribute__((ext_vector_type(8))) short bf16x8;
typedef __attribute__((ext_vector_type(4))) float f32x4;

union fui { float f; unsigned u; };

static __device__ inline short f2bf(float x) {            // RNE-ish rounding
    union { float f; unsigned u; } v; v.f = x;
    unsigned r = v.u + 0x7fff + ((v.u >> 16) & 1);
    return (short)(r >> 16);
}
// truncation split: hi = trunc16(f), lo = trunc16(f - hi); |err| ~ 2^-17 rel
static __device__ inline void split1(float f, short* h, short* l) {
    fui a; a.f = f;
    *h = (short)(a.u >> 16);
    fui t; t.u = a.u & 0xffff0000u;
    fui r; r.f = f - t.f;
    *l = (short)(r.u >> 16);
}

#define MFMA16(a, b, c) __builtin_amdgcn_mfma_f32_16x16x32_bf16((a), (b), (c), 0, 0, 0)

#define GLDS16(g, l) __builtin_amdgcn_global_load_lds(                        \
    (const __attribute__((address_space(1))) unsigned int*)(g),               \
    (__attribute__((address_space(3))) unsigned int*)(l), 16, 0, 0)

static __device__ inline void split4_store(const float4 f, short4* Hp, short4* Lp)
{
    fui a[4]; a[0].f = f.x; a[1].f = f.y; a[2].f = f.z; a[3].f = f.w;
    union { short s[4]; short4 v; } H, L;
#pragma unroll
    for (int j = 0; j < 4; ++j) {
        H.s[j] = (short)(a[j].u >> 16);
        fui t; t.u = a[j].u & 0xffff0000u;
        fui r; r.f = a[j].f - t.f;
        L.s[j] = (short)(r.u >> 16);
    }
    *Hp = H.v; *Lp = L.v;
}

// ---------------------------------------------------------------------------
// Pre-split fp32 matrix into hi/lo bf16 (activations between GEMM phases).
// ---------------------------------------------------------------------------
__global__ __launch_bounds__(256)
void wsplit_kernel(const float* __restrict__ W, short* __restrict__ Wh,
                   short* __restrict__ Wl)
{
    const size_t i = (size_t)blockIdx.x * 256 + threadIdx.x;
    split4_store(((const float4*)W)[i], &((short4*)Wh)[i], &((short4*)Wl)[i]);
}

// ---------------------------------------------------------------------------
// Fused preprocessing (one launch): 4 weight splits | query split | mask flags.
// Role chosen by block range; all paths LDS-free, block-uniform branching.
//   bid in [0,4096)        : weight split, which = bid>>10
//   bid in [4096,12288)    : query split -> Xh/Xl
//   bid in [12288,13312)   : mask flags
// ---------------------------------------------------------------------------
__global__ __launch_bounds__(256)
void preproc_kernel(const float* __restrict__ W0, const float* __restrict__ W1,
                    const float* __restrict__ W2, const float* __restrict__ W3,
                    const float* __restrict__ query,
                    short* __restrict__ Whd, short* __restrict__ Wld,
                    short* __restrict__ Xh, short* __restrict__ Xl,
                    const unsigned char* __restrict__ mask, int* __restrict__ flags)
{
    const int bid = blockIdx.x;
    const int tid = threadIdx.x;
    if (bid < 4096) {
        const int which = bid >> 10;
        const float* W = (which == 0) ? W0 : (which == 1) ? W1 : (which == 2) ? W2 : W3;
        const size_t i = (size_t)(bid & 1023) * 256 + tid;
        short* Hd = Whd + (size_t)which * 2 * D_SZ * D_SZ;   // wqh wql wkh wkl ...
        short* Ld = Wld + (size_t)which * 2 * D_SZ * D_SZ;
        split4_store(((const float4*)W)[i], &((short4*)Hd)[i], &((short4*)Ld)[i]);
    } else if (bid < 12288) {
        const size_t i = (size_t)(bid - 4096) * 256 + tid;
        split4_store(((const float4*)query)[i], &((short4*)Xh)[i], &((short4*)Xl)[i]);
    } else {
        const int f = (bid - 12288) * 4 + (tid >> 6);
        const int lane = tid & 63;
        const int b = f >> 10, qt = (f >> 5) & 31, kt = f & 31;
        const unsigned char* base = mask + ((size_t)b * T_SZ + qt * 64) * T_SZ + kt * 64;
        bool nz = false;
#pragma unroll
        for (int i2 = 0; i2 < 4; ++i2) {
            const int c = lane + 64 * i2;
            const int row = c >> 2, off = (c & 3) * 16;
            uint4 v = *(const uint4*)(base + (size_t)row * T_SZ + off);
            nz |= ((v.x | v.y | v.z | v.w) != 0);
        }
        unsigned long long bal = __ballot(nz);
        if (lane == 0) flags[f] = (bal != 0) ? 1 : 0;
    }
}

// ---------------------------------------------------------------------------
// QKV projection. W (pre-split) staged via GLDS, 2-phase double-buffered;
// A (pre-split bf16) read DIRECTLY from global as per-lane b128 fragments
// (L2-hot: 8 n-blocks on same XCD share A). LDS 64->32KB => 4 blocks/CU
// (16 waves, was 8). launch_bounds(256,4) pins VGPR <= 128.
// Epilogue: which<2 -> RoPE in-register (q pre-scaled 1/8); v -> bf16.
// ---------------------------------------------------------------------------
__global__ __launch_bounds__(256, 4)
void qkv_mfma_kernel(const short* __restrict__ Ah, const short* __restrict__ Al,
                     const short* __restrict__ Wh, const short* __restrict__ Wl,
                     const float* __restrict__ bias,
                     const float* __restrict__ cosb, const float* __restrict__ sinb,
                     short* __restrict__ Hd, short* __restrict__ Ld,
                     short* __restrict__ Vb, const int which)
{
    __shared__ __align__(16) short Whs[2][4096];
    __shared__ __align__(16) short Wls[2][4096];

    const int m0 = blockIdx.x * 128, n0 = blockIdx.y * 128;
    const int tid = threadIdx.x;
    const int wv = tid >> 6, lane = tid & 63;
    const int wm = wv >> 1, wn = wv & 1;
    const int l15 = lane & 15, quad = lane >> 4;

    f32x4 acc[4][4];
#pragma unroll
    for (int mt = 0; mt < 4; ++mt)
#pragma unroll
        for (int nt = 0; nt < 4; ++nt)
            acc[mt][nt] = (f32x4){0.f, 0.f, 0.f, 0.f};

    // direct global A-fragment pointers (advance by k0)
    const short* aph[4];
    const short* apl[4];
#pragma unroll
    for (int mt = 0; mt < 4; ++mt) {
        const size_t ro = (size_t)(m0 + wm * 64 + mt * 16 + l15) * D_SZ + quad * 8;
        aph[mt] = Ah + ro;
        apl[mt] = Al + ro;
    }

    const size_t woff = (size_t)(n0 + wv * 32 + (lane >> 2)) * D_SZ + (lane & 3) * 8;
    const short* whg = Wh + woff;
    const short* wlg = Wl + woff;

#define STAGEW(bi, kk)                                                        \
    do {                                                                      \
        short* w0 = &Whs[bi][wv * 1024];                                      \
        short* w1 = &Wls[bi][wv * 1024];                                      \
        GLDS16(whg + (kk),             w0);                                   \
        GLDS16(whg + 16 * D_SZ + (kk), w0 + 512);                             \
        GLDS16(wlg + (kk),             w1);                                   \
        GLDS16(wlg + 16 * D_SZ + (kk), w1 + 512);                             \
    } while (0)

    STAGEW(0, 0);
    for (int k0 = 0; k0 < D_SZ; k0 += 32) {
        const int cur = (k0 >> 5) & 1;
        __syncthreads();                       // drains this tile's W loads
        if (k0 + 32 < D_SZ) STAGEW(cur ^ 1, k0 + 32);

        bf16x8 ah[4], al[4];
#pragma unroll
        for (int mt = 0; mt < 4; ++mt) {
            ah[mt] = *(const bf16x8*)(aph[mt] + k0);
            al[mt] = *(const bf16x8*)(apl[mt] + k0);
        }
#pragma unroll
        for (int nt = 0; nt < 4; ++nt) {
            const int brow = (wn * 64 + nt * 16 + l15) * 32 + quad * 8;
            const bf16x8 bh = *(const bf16x8*)&Whs[cur][brow];
            const bf16x8 bl = *(const bf16x8*)&Wls[cur][brow];
#pragma unroll
            for (int mt = 0; mt < 4; ++mt) {
                acc[mt][nt] = MFMA16(ah[mt], bh, acc[mt][nt]);
                acc[mt][nt] = MFMA16(al[mt], bh, acc[mt][nt]);
                acc[mt][nt] = MFMA16(ah[mt], bl, acc[mt][nt]);
            }
        }
    }
#undef STAGEW

    const int hh = (blockIdx.y << 1) + wn;     // head index
    if (which < 2) {
        const float qscale = (which == 0) ? 0.125f : 1.0f;
#pragma unroll
        for (int mt = 0; mt < 4; ++mt)
#pragma unroll
            for (int p = 0; p < 2; ++p) {
                const int d1 = p * 16 + l15, d2 = d1 + 32;
                const int col1 = n0 + wn * 64 + d1;
                const float b1 = bias[col1], b2 = bias[col1 + 32];
#pragma unroll
                for (int r = 0; r < 4; ++r) {
                    const int m = m0 + wm * 64 + mt * 16 + quad * 4 + r;
                    const int bb = m >> 11, tg = m & (T_SZ - 1);
                    const float c1 = cosb[tg * 64 + d1], s1 = sinb[tg * 64 + d1];
                    const float c2 = cosb[tg * 64 + d2], s2 = sinb[tg * 64 + d2];
                    const float x1 = acc[mt][p][r] + b1;
                    const float x2 = acc[mt][p + 2][r] + b2;
                    const float y1 = (x1 * c1 - x2 * s1) * qscale;
                    const float y2 = (x2 * c2 + x1 * s2) * qscale;
                    const size_t base = (((size_t)(bb * H_SZ + hh)) * T_SZ + tg) * 64;
                    short h_, l_;
                    split1(y1, &h_, &l_); Hd[base + d1] = h_; Ld[base + d1] = l_;
                    split1(y2, &h_, &l_); Hd[base + d2] = h_; Ld[base + d2] = l_;
                }
            }
    } else {
#pragma unroll
        for (int nt = 0; nt < 4; ++nt) {
            const int d = nt * 16 + l15;
            const float bvv = bias[n0 + wn * 64 + d];
#pragma unroll
            for (int mt = 0; mt < 4; ++mt)
#pragma unroll
                for (int r = 0; r < 4; ++r) {
                    const int m = m0 + wm * 64 + mt * 16 + quad * 4 + r;
                    const int bb = m >> 11, tg = m & (T_SZ - 1);
                    Vb[(((size_t)(bb * H_SZ + hh)) * T_SZ + tg) * 64 + d] =
                        f2bf(acc[mt][nt][r] + bvv);
                }
        }
    }
}

// ---------------------------------------------------------------------------
// Output projection GEMM, same structure: W staged (2-phase), A direct-global.
// ---------------------------------------------------------------------------
__global__ __launch_bounds__(256, 4)
void gemm_out_kernel(const short* __restrict__ Ah, const short* __restrict__ Al,
                     const short* __restrict__ Wh, const short* __restrict__ Wl,
                     const float* __restrict__ bias, float* __restrict__ C)
{
    __shared__ __align__(16) short Whs[2][4096];
    __shared__ __align__(16) short Wls[2][4096];

    const int m0 = blockIdx.x * 128, n0 = blockIdx.y * 128;
    const int tid = threadIdx.x;
    const int wv = tid >> 6, lane = tid & 63;
    const int wm = wv >> 1, wn = wv & 1;
    const int l15 = lane & 15, quad = lane >> 4;

    f32x4 acc[4][4];
#pragma unroll
    for (int mt = 0; mt < 4; ++mt)
#pragma unroll
        for (int nt = 0; nt < 4; ++nt)
            acc[mt][nt] = (f32x4){0.f, 0.f, 0.f, 0.f};

    const short* aph[4];
    const short* apl[4];
#pragma unroll
    for (int mt = 0; mt < 4; ++mt) {
        const size_t ro = (size_t)(m0 + wm * 64 + mt * 16 + l15) * D_SZ + quad * 8;
        aph[mt] = Ah + ro;
        apl[mt] = Al + ro;
    }

    const size_t woff = (size_t)(n0 + wv * 32 + (lane >> 2)) * D_SZ + (lane & 3) * 8;
    const short* whg = Wh + woff;
    const short* wlg = Wl + woff;

#define STAGEW(bi, kk)                                                        \
    do {                                                                      \
        short* w0 = &Whs[bi][wv * 1024];                                      \
        short* w1 = &Wls[bi][wv * 1024];                                      \
        GLDS16(whg + (kk),             w0);                                   \
        GLDS16(whg + 16 * D_SZ + (kk), w0 + 512);                             \
        GLDS16(wlg + (kk),             w1);                                   \
        GLDS16(wlg + 16 * D_SZ + (kk), w1 + 512);                             \
    } while (0)

    STAGEW(0, 0);
    for (int k0 = 0; k0 < D_SZ; k0 += 32) {
        const int cur = (k0 >> 5) & 1;
        __syncthreads();
        if (k0 + 32 < D_SZ) STAGEW(cur ^ 1, k0 + 32);

        bf16x8 ah[4], al[4];
#pragma unroll
        for (int mt = 0; mt < 4; ++mt) {
            ah[mt] = *(const bf16x8*)(aph[mt] + k0);
            al[mt] = *(const bf16x8*)(apl[mt] + k0);
        }
#pragma unroll
        for (int nt = 0; nt < 4; ++nt) {
            const int brow = (wn * 64 + nt * 16 + l15) * 32 + quad * 8;
            const bf16x8 bh = *(const bf16x8*)&Whs[cur][brow];
            const bf16x8 bl = *(const bf16x8*)&Wls[cur][brow];
#pragma unroll
            for (int mt = 0; mt < 4; ++mt) {
                acc[mt][nt] = MFMA16(ah[mt], bh, acc[mt][nt]);
                acc[mt][nt] = MFMA16(al[mt], bh, acc[mt][nt]);
                acc[mt][nt] = MFMA16(ah[mt], bl, acc[mt][nt]);
            }
        }
    }
#undef STAGEW

#pragma unroll
    for (int nt = 0; nt < 4; ++nt) {
        const int col = n0 + wn * 64 + nt * 16 + l15;
        const float bvv = bias[col];
#pragma unroll
        for (int mt = 0; mt < 4; ++mt)
#pragma unroll
            for (int r = 0; r < 4; ++r) {
                const int m = m0 + wm * 64 + mt * 16 + quad * 4 + r;
                C[(size_t)m * D_SZ + col] = acc[mt][nt][r] + bvv;
            }
    }
}

// ---------------------------------------------------------------------------
// MFMA flash attention (R7-measured structure). QBLK=64 (4wv x 16q).
// T14 async-STAGE prefetch; conflict-free V transpose staging; __expf softmax.
// Separate Ps buffer (R10: P-alias did not raise occupancy; its barrier cost
// +11us). __launch_bounds__(256,6) pins VGPR <= 85 (cliff: 84->30%, 88->22%).
// R8 lesson: do not add staging pointers to this body (spill cascade).
// Output written pre-split hi/lo bf16 for gemm_out staging.
// ---------------------------------------------------------------------------
__global__ __launch_bounds__(256, 6)
void attn_mfma_kernel(const short* __restrict__ Qhg, const short* __restrict__ Qlg,
                      const short* __restrict__ Khg, const short* __restrict__ Klg,
                      const short* __restrict__ Vg,
                      const unsigned char* __restrict__ mask,
                      const int* __restrict__ flags,
                      short* __restrict__ Oh, short* __restrict__ Ol)
{
    __shared__ __align__(16) short Khs[64 * 72];
    __shared__ __align__(16) short Kls[64 * 72];
    __shared__ __align__(16) short Vt[64 * 72];       // [d][t]
    __shared__ __align__(16) short Ps[4 * 16 * 72];   // per-wave P tiles

    const int bh = blockIdx.y;
    const int b = bh >> 4, h = bh & 15;
    const int q0 = blockIdx.x * 64;
    const int tid = threadIdx.x;
    const int wv = tid >> 6, lane = tid & 63;
    const int l15 = lane & 15, quad = lane >> 4;

    // Q fragments: direct bf16 loads (A-layout: m=l15, k=quad*8+j)
    const short* qhp = Qhg + ((size_t)bh * T_SZ + q0 + wv * 16 + l15) * 64 + quad * 8;
    const short* qlp = Qlg + ((size_t)bh * T_SZ + q0 + wv * 16 + l15) * 64 + quad * 8;
    bf16x8 qh[2], ql[2];
#pragma unroll
    for (int s = 0; s < 2; ++s) {
        qh[s] = *(const bf16x8*)(qhp + 32 * s);
        ql[s] = *(const bf16x8*)(qlp + 32 * s);
    }

    f32x4 accO[4];
#pragma unroll
    for (int nt = 0; nt < 4; ++nt) accO[nt] = (f32x4){0.f, 0.f, 0.f, 0.f};
    float m_i[4], l_i[4];
#pragma unroll
    for (int r = 0; r < 4; ++r) { m_i[r] = -1e30f; l_i[r] = 0.f; }

    const short* khb = Khg + (size_t)bh * T_SZ * 64;
    const short* klb = Klg + (size_t)bh * T_SZ * 64;
    const short* vb  = Vg  + (size_t)bh * T_SZ * 64;
    const unsigned char* mbase = mask + ((size_t)b * T_SZ + q0) * T_SZ;
    const int* frow = flags + ((size_t)b * 32 + blockIdx.x) * 32;

    // Per-thread fixed addressing for K/V staging.
    const short* kgp[4];   // global sources (advance by kt*64)
    short*       kld[4];   // LDS destinations (fixed)
#pragma unroll
    for (int jj = 0; jj < 4; ++jj) {
        const int cc = tid + 256 * (jj & 1);
        const int row = cc >> 3, off = (cc & 7) * 8;
        kgp[jj] = ((jj < 2) ? khb : klb) + (size_t)row * 64 + off;
        kld[jj] = ((jj < 2) ? Khs : Kls) + row * 72 + off;
    }
    const int vt0 = (tid & 15) * 4, vd0 = (tid >> 4) * 4;
    const short* vgp[4];
#pragma unroll
    for (int i = 0; i < 4; ++i)
        vgp[i] = vb + (size_t)(vt0 + i) * 64 + vd0;
    short* pw = &Ps[wv * 16 * 72];

    // staging registers (tile kti+1 in flight during compute of kti)
    bf16x8 kst[4];
    uint2  rv[4];
#pragma unroll
    for (int jj = 0; jj < 4; ++jj) kst[jj] = *(const bf16x8*)(kgp[jj]);
#pragma unroll
    for (int i = 0; i < 4; ++i)    rv[i]   = *(const uint2*)(vgp[i]);

    for (int kti = 0; kti < 32; ++kti) {
        const int kt = kti * 64;
        __syncthreads();
        // ---- drain staged K regs -> LDS
#pragma unroll
        for (int jj = 0; jj < 4; ++jj)
            *(bf16x8*)kld[jj] = kst[jj];
        // ---- V: register 4x4 transpose -> Vt[d][t], conflict-free writes
#pragma unroll
        for (int c = 0; c < 4; ++c) {
            const int k = c >> 1;
            const unsigned sel = (c & 1) ? 0x07060302u : 0x05040100u;
            const unsigned lo0 = k ? rv[0].y : rv[0].x;
            const unsigned lo1 = k ? rv[1].y : rv[1].x;
            const unsigned lo2 = k ? rv[2].y : rv[2].x;
            const unsigned lo3 = k ? rv[3].y : rv[3].x;
            uint2 o;
            o.x = __builtin_amdgcn_perm(lo1, lo0, sel);  // (t0.c, t1.c)
            o.y = __builtin_amdgcn_perm(lo3, lo2, sel);  // (t2.c, t3.c)
            *(uint2*)&Vt[(vd0 + c) * 72 + vt0] = o;
        }
        // ---- issue next-tile global loads; latency hides under compute below
        if (kti < 31) {
            const size_t adv = (size_t)(kt + 64) * 64;
#pragma unroll
            for (int jj = 0; jj < 4; ++jj)
                kst[jj] = *(const bf16x8*)(kgp[jj] + adv);
#pragma unroll
            for (int i = 0; i < 4; ++i)
                rv[i] = *(const uint2*)(vgp[i] + adv);
        }
        __syncthreads();

        // ---- S = Q K^T (split bf16, 3 products; scale pre-folded into Q)
        f32x4 accS[4];
        __builtin_amdgcn_s_setprio(1);
#pragma unroll
        for (int nt = 0; nt < 4; ++nt) {
            f32x4 acc = (f32x4){0.f, 0.f, 0.f, 0.f};
#pragma unroll
            for (int s = 0; s < 2; ++s) {
                const bf16x8 kh = *(const bf16x8*)&Khs[(nt * 16 + l15) * 72 + 32 * s + quad * 8];
                const bf16x8 kl = *(const bf16x8*)&Kls[(nt * 16 + l15) * 72 + 32 * s + quad * 8];
                acc = MFMA16(qh[s], kh, acc);
                acc = MFMA16(ql[s], kh, acc);
                acc = MFMA16(qh[s], kl, acc);
            }
            accS[nt] = acc;
        }
        __builtin_amdgcn_s_setprio(0);

        float sv[4][4];   // [nt][r]
        if (frow[kti]) {  // rare masked path
#pragma unroll
            for (int nt = 0; nt < 4; ++nt)
#pragma unroll
                for (int r = 0; r < 4; ++r) {
                    const unsigned char mb =
                        mbase[(size_t)(wv * 16 + quad * 4 + r) * T_SZ + kt + nt * 16 + l15];
                    sv[nt][r] = mb ? -1e30f : accS[nt][r];
                }
        } else {
#pragma unroll
            for (int nt = 0; nt < 4; ++nt)
#pragma unroll
                for (int r = 0; r < 4; ++r)
                    sv[nt][r] = accS[nt][r];
        }

        // ---- online softmax; only the row-max is cross-lane per tile
        float rmax[4];
#pragma unroll
        for (int r = 0; r < 4; ++r)
            rmax[r] = fmaxf(fmaxf(sv[0][r], sv[1][r]), fmaxf(sv[2][r], sv[3][r]));
#pragma unroll
        for (int off = 1; off < 16; off <<= 1)
#pragma unroll
            for (int r = 0; r < 4; ++r)
                rmax[r] = fmaxf(rmax[r], __shfl_xor(rmax[r], off, 64));

        float alpha[4];
#pragma unroll
        for (int r = 0; r < 4; ++r) {
            const float mnew = fmaxf(m_i[r], rmax[r]);
            alpha[r] = __expf(m_i[r] - mnew);
            m_i[r] = mnew;
        }
        float lsum[4] = {0.f, 0.f, 0.f, 0.f};
#pragma unroll
        for (int nt = 0; nt < 4; ++nt)
#pragma unroll
            for (int r = 0; r < 4; ++r) {
                const float p = __expf(sv[nt][r] - m_i[r]);
                sv[nt][r] = p;
                lsum[r] += p;
            }
#pragma unroll
        for (int r = 0; r < 4; ++r)
            l_i[r] = l_i[r] * alpha[r] + lsum[r];   // lane-partial; reduced at end

        // ---- P -> bf16 (round-half-up) -> per-wave LDS tile
#pragma unroll
        for (int nt = 0; nt < 4; ++nt)
#pragma unroll
            for (int r = 0; r < 4; ++r) {
                fui u; u.f = sv[nt][r];
                pw[(quad * 4 + r) * 72 + nt * 16 + l15] = (short)((u.u + 0x8000u) >> 16);
            }

        // ---- O = O*alpha + P @ V
#pragma unroll
        for (int nt = 0; nt < 4; ++nt)
#pragma unroll
            for (int r = 0; r < 4; ++r)
                accO[nt][r] *= alpha[r];

        bf16x8 pa[2];
#pragma unroll
        for (int s = 0; s < 2; ++s)
            pa[s] = *(const bf16x8*)&pw[l15 * 72 + 32 * s + quad * 8];
        __builtin_amdgcn_s_setprio(1);
#pragma unroll
        for (int nt = 0; nt < 4; ++nt)
#pragma unroll
            for (int s = 0; s < 2; ++s) {
                const bf16x8 vf = *(const bf16x8*)&Vt[(nt * 16 + l15) * 72 + 32 * s + quad * 8];
                accO[nt] = MFMA16(pa[s], vf, accO[nt]);
            }
        __builtin_amdgcn_s_setprio(0);
    }

    // final cross-lane reduction of l partials (m_i already lane-uniform)
#pragma unroll
    for (int off = 1; off < 16; off <<= 1)
#pragma unroll
        for (int r = 0; r < 4; ++r)
            l_i[r] += __shfl_xor(l_i[r], off, 64);

#pragma unroll
    for (int r = 0; r < 4; ++r) {
        const float inv = 1.f / l_i[r];
        const int t = q0 + wv * 16 + quad * 4 + r;
        const size_t base = ((size_t)(b * T_SZ + t)) * D_SZ + h * DK_SZ;
#pragma unroll
        for (int nt = 0; nt < 4; ++nt) {
            short h_, l_;
            split1(accO[nt][r] * inv, &h_, &l_);
            Oh[base + nt * 16 + l15] = h_;
            Ol[base + nt * 16 + l15] = l_;
        }
    }
}

// ---------------------------------------------------------------------------
extern "C" void kernel_launch(void* const* d_in, const int* in_sizes, int n_in,
                              void* d_out, int out_size, void* d_ws, size_t ws_size,
                              hipStream_t stream)
{
    const float* query = (const float*)d_in[0];
    const float* key   = (const float*)d_in[1];
    const float* value = (const float*)d_in[2];
    const float* cosb  = (const float*)d_in[3];
    const float* sinb  = (const float*)d_in[4];
    const unsigned char* mask = (const unsigned char*)d_in[5];
    const float* Wq = (const float*)d_in[6];
    const float* bq = (const float*)d_in[7];
    const float* Wk = (const float*)d_in[8];
    const float* bk = (const float*)d_in[9];
    const float* Wv = (const float*)d_in[10];
    const float* bv = (const float*)d_in[11];
    const float* Wo = (const float*)d_in[12];
    const float* bo = (const float*)d_in[13];
    float* out = (float*)d_out;

    // workspace layout (shorts): Qh Ql Kh Kl Vb (5*eb, 80MB) |
    // Xh Xl (2*eb, 32MB: A-split during qkv phase, attn-output split after) |
    // 8x weight splits (16MB) | flags (16KB)  -> ~134MB total
    short* sp = (short*)d_ws;
    const size_t eb = (size_t)B_SZ * H_SZ * T_SZ * DK_SZ;   // 8388608 elems
    short* Qh = sp;          short* Ql = sp + eb;
    short* Kh = sp + 2 * eb; short* Kl = sp + 3 * eb;
    short* Vb = sp + 4 * eb;
    short* Xh = sp + 5 * eb; short* Xl = sp + 6 * eb;       // time-shared region
    short* wsp = sp + 7 * eb;
    const size_t wlen = (size_t)D_SZ * D_SZ;
    short* wqh = wsp;            short* wql = wsp + wlen;
    short* wkh = wsp + 2 * wlen; short* wkl = wsp + 3 * wlen;
    short* wvh = wsp + 4 * wlen; short* wvl = wsp + 5 * wlen;
    short* woh = wsp + 6 * wlen; short* wol = wsp + 7 * wlen;
    int* flags = (int*)(wsp + 8 * wlen);

    const int aBlocks = (int)((size_t)M_SZ * D_SZ / 4 / 256);         // 8192
    // fused preprocessing: 4 weight splits + query split + mask flags
    preproc_kernel<<<4096 + 8192 + 1024, 256, 0, stream>>>(
        Wq, Wk, Wv, Wo, query, wqh, wql, Xh, Xl, mask, flags);

    // q / k / v projections; X region serially reused for the A-splits
    qkv_mfma_kernel<<<dim3(M_SZ / 128, 8), 256, 0, stream>>>(
        Xh, Xl, wqh, wql, bq, cosb, sinb, Qh, Ql, Vb, 0);
    wsplit_kernel<<<aBlocks, 256, 0, stream>>>(key, Xh, Xl);
    qkv_mfma_kernel<<<dim3(M_SZ / 128, 8), 256, 0, stream>>>(
        Xh, Xl, wkh, wkl, bk, cosb, sinb, Kh, Kl, Vb, 1);
    wsplit_kernel<<<aBlocks, 256, 0, stream>>>(value, Xh, Xl);
    qkv_mfma_kernel<<<dim3(M_SZ / 128, 8), 256, 0, stream>>>(
        Xh, Xl, wvh, wvl, bv, cosb, sinb, Qh, Ql, Vb, 2);

    // attention writes its output pre-split into the (now free) X region
    attn_mfma_kernel<<<dim3(T_SZ / 64, B_SZ * H_SZ), 256, 0, stream>>>(
        Qh, Ql, Kh, Kl, Vb, mask, flags, Xh, Xl);

    gemm_out_kernel<<<dim3(M_SZ / 128, D_SZ / 128), 256, 0, stream>>>(
        Xh, Xl, woh, wol, bo, out);
}

// Round 13
// 641.101 us; speedup vs baseline: 1.3539x; 1.3539x over previous
//
#include <hip/hip_runtime.h>

#define B_SZ 4
#define T_SZ 2048
#define D_SZ 1024
#define H_SZ 16
#define DK_SZ 64
#define M_SZ (B_SZ * T_SZ)  // 8192

typedef __attribute__((ext_vector_type(8))) short bf16x8;
typedef __attribute__((ext_vector_type(4))) float f32x4;

union fui { float f; unsigned u; };

static __device__ inline short f2bf(float x) {            // RNE-ish rounding
    union { float f; unsigned u; } v; v.f = x;
    unsigned r = v.u + 0x7fff + ((v.u >> 16) & 1);
    return (short)(r >> 16);
}
// truncation split: hi = trunc16(f), lo = trunc16(f - hi); |err| ~ 2^-17 rel
static __device__ inline void split1(float f, short* h, short* l) {
    fui a; a.f = f;
    *h = (short)(a.u >> 16);
    fui t; t.u = a.u & 0xffff0000u;
    fui r; r.f = f - t.f;
    *l = (short)(r.u >> 16);
}

#define MFMA16(a, b, c) __builtin_amdgcn_mfma_f32_16x16x32_bf16((a), (b), (c), 0, 0, 0)

#define GLDS16(g, l) __builtin_amdgcn_global_load_lds(                        \
    (const __attribute__((address_space(1))) unsigned int*)(g),               \
    (__attribute__((address_space(3))) unsigned int*)(l), 16, 0, 0)

static __device__ inline void split4_store(const float4 f, short4* Hp, short4* Lp)
{
    fui a[4]; a[0].f = f.x; a[1].f = f.y; a[2].f = f.z; a[3].f = f.w;
    union { short s[4]; short4 v; } H, L;
#pragma unroll
    for (int j = 0; j < 4; ++j) {
        H.s[j] = (short)(a[j].u >> 16);
        fui t; t.u = a[j].u & 0xffff0000u;
        fui r; r.f = a[j].f - t.f;
        L.s[j] = (short)(r.u >> 16);
    }
    *Hp = H.v; *Lp = L.v;
}

// ---------------------------------------------------------------------------
// Pre-split fp32 matrix into hi/lo bf16 (activations between GEMM phases).
// ---------------------------------------------------------------------------
__global__ __launch_bounds__(256)
void wsplit_kernel(const float* __restrict__ W, short* __restrict__ Wh,
                   short* __restrict__ Wl)
{
    const size_t i = (size_t)blockIdx.x * 256 + threadIdx.x;
    split4_store(((const float4*)W)[i], &((short4*)Wh)[i], &((short4*)Wl)[i]);
}

// ---------------------------------------------------------------------------
// Fused preprocessing (one launch): 4 weight splits | query split | mask flags.
// Role chosen by block range; all paths LDS-free, block-uniform branching.
//   bid in [0,4096)        : weight split, which = bid>>10
//   bid in [4096,12288)    : query split -> Xh/Xl
//   bid in [12288,13312)   : mask flags
// ---------------------------------------------------------------------------
__global__ __launch_bounds__(256)
void preproc_kernel(const float* __restrict__ W0, const float* __restrict__ W1,
                    const float* __restrict__ W2, const float* __restrict__ W3,
                    const float* __restrict__ query,
                    short* __restrict__ Whd, short* __restrict__ Wld,
                    short* __restrict__ Xh, short* __restrict__ Xl,
                    const unsigned char* __restrict__ mask, int* __restrict__ flags)
{
    const int bid = blockIdx.x;
    const int tid = threadIdx.x;
    if (bid < 4096) {
        const int which = bid >> 10;
        const float* W = (which == 0) ? W0 : (which == 1) ? W1 : (which == 2) ? W2 : W3;
        const size_t i = (size_t)(bid & 1023) * 256 + tid;
        short* Hd = Whd + (size_t)which * 2 * D_SZ * D_SZ;   // wqh wql wkh wkl ...
        short* Ld = Wld + (size_t)which * 2 * D_SZ * D_SZ;
        split4_store(((const float4*)W)[i], &((short4*)Hd)[i], &((short4*)Ld)[i]);
    } else if (bid < 12288) {
        const size_t i = (size_t)(bid - 4096) * 256 + tid;
        split4_store(((const float4*)query)[i], &((short4*)Xh)[i], &((short4*)Xl)[i]);
    } else {
        const int f = (bid - 12288) * 4 + (tid >> 6);
        const int lane = tid & 63;
        const int b = f >> 10, qt = (f >> 5) & 31, kt = f & 31;
        const unsigned char* base = mask + ((size_t)b * T_SZ + qt * 64) * T_SZ + kt * 64;
        bool nz = false;
#pragma unroll
        for (int i2 = 0; i2 < 4; ++i2) {
            const int c = lane + 64 * i2;
            const int row = c >> 2, off = (c & 3) * 16;
            uint4 v = *(const uint4*)(base + (size_t)row * T_SZ + off);
            nz |= ((v.x | v.y | v.z | v.w) != 0);
        }
        unsigned long long bal = __ballot(nz);
        if (lane == 0) flags[f] = (bal != 0) ? 1 : 0;
    }
}

// ---------------------------------------------------------------------------
// QKV projection, 2-phase double-buffered: GLDS for K-step k+1 issued before
// computing k; ONE barrier per K-step. A and W both pre-split hi/lo bf16.
// R12 lesson: A MUST be staged via global_load_lds (coalesced wave-level
// transactions) — direct per-lane b128 A reads cost +200us (uncoalesced).
// Epilogue: which<2 -> RoPE in-register (q pre-scaled 1/8); v -> bf16.
// ---------------------------------------------------------------------------
__global__ __launch_bounds__(256)
void qkv_mfma_kernel(const short* __restrict__ Ah, const short* __restrict__ Al,
                     const short* __restrict__ Wh, const short* __restrict__ Wl,
                     const float* __restrict__ bias,
                     const float* __restrict__ cosb, const float* __restrict__ sinb,
                     short* __restrict__ Hd, short* __restrict__ Ld,
                     short* __restrict__ Vb, const int which)
{
    __shared__ __align__(16) short Ahs[2][4096];
    __shared__ __align__(16) short Als[2][4096];
    __shared__ __align__(16) short Whs[2][4096];
    __shared__ __align__(16) short Wls[2][4096];

    const int m0 = blockIdx.x * 128, n0 = blockIdx.y * 128;
    const int tid = threadIdx.x;
    const int wv = tid >> 6, lane = tid & 63;
    const int wm = wv >> 1, wn = wv & 1;
    const int l15 = lane & 15, quad = lane >> 4;

    f32x4 acc[4][4];
#pragma unroll
    for (int mt = 0; mt < 4; ++mt)
#pragma unroll
        for (int nt = 0; nt < 4; ++nt)
            acc[mt][nt] = (f32x4){0.f, 0.f, 0.f, 0.f};

    const size_t aoff = (size_t)(m0 + wv * 32 + (lane >> 2)) * D_SZ + (lane & 3) * 8;
    const size_t woff = (size_t)(n0 + wv * 32 + (lane >> 2)) * D_SZ + (lane & 3) * 8;
    const short* ahg = Ah + aoff;
    const short* alg = Al + aoff;
    const short* whg = Wh + woff;
    const short* wlg = Wl + woff;

#define STAGEQ(bi, kk)                                                        \
    do {                                                                      \
        short* a0 = &Ahs[bi][wv * 1024];                                      \
        short* a1 = &Als[bi][wv * 1024];                                      \
        short* w0 = &Whs[bi][wv * 1024];                                      \
        short* w1 = &Wls[bi][wv * 1024];                                      \
        GLDS16(ahg + (kk),             a0);                                   \
        GLDS16(ahg + 16 * D_SZ + (kk), a0 + 512);                             \
        GLDS16(alg + (kk),             a1);                                   \
        GLDS16(alg + 16 * D_SZ + (kk), a1 + 512);                             \
        GLDS16(whg + (kk),             w0);                                   \
        GLDS16(whg + 16 * D_SZ + (kk), w0 + 512);                             \
        GLDS16(wlg + (kk),             w1);                                   \
        GLDS16(wlg + 16 * D_SZ + (kk), w1 + 512);                             \
    } while (0)

    STAGEQ(0, 0);
    for (int k0 = 0; k0 < D_SZ; k0 += 32) {
        const int cur = (k0 >> 5) & 1;
        __syncthreads();                       // drains this tile's loads
        if (k0 + 32 < D_SZ) STAGEQ(cur ^ 1, k0 + 32);

        bf16x8 ah[4], al[4];
#pragma unroll
        for (int mt = 0; mt < 4; ++mt) {
            const int arow = (wm * 64 + mt * 16 + l15) * 32 + quad * 8;
            ah[mt] = *(const bf16x8*)&Ahs[cur][arow];
            al[mt] = *(const bf16x8*)&Als[cur][arow];
        }
#pragma unroll
        for (int nt = 0; nt < 4; ++nt) {
            const int brow = (wn * 64 + nt * 16 + l15) * 32 + quad * 8;
            const bf16x8 bh = *(const bf16x8*)&Whs[cur][brow];
            const bf16x8 bl = *(const bf16x8*)&Wls[cur][brow];
#pragma unroll
            for (int mt = 0; mt < 4; ++mt) {
                acc[mt][nt] = MFMA16(ah[mt], bh, acc[mt][nt]);
                acc[mt][nt] = MFMA16(al[mt], bh, acc[mt][nt]);
                acc[mt][nt] = MFMA16(ah[mt], bl, acc[mt][nt]);
            }
        }
    }
#undef STAGEQ

    const int hh = (blockIdx.y << 1) + wn;     // head index
    if (which < 2) {
        const float qscale = (which == 0) ? 0.125f : 1.0f;
#pragma unroll
        for (int mt = 0; mt < 4; ++mt)
#pragma unroll
            for (int p = 0; p < 2; ++p) {
                const int d1 = p * 16 + l15, d2 = d1 + 32;
                const int col1 = n0 + wn * 64 + d1;
                const float b1 = bias[col1], b2 = bias[col1 + 32];
#pragma unroll
                for (int r = 0; r < 4; ++r) {
                    const int m = m0 + wm * 64 + mt * 16 + quad * 4 + r;
                    const int bb = m >> 11, tg = m & (T_SZ - 1);
                    const float c1 = cosb[tg * 64 + d1], s1 = sinb[tg * 64 + d1];
                    const float c2 = cosb[tg * 64 + d2], s2 = sinb[tg * 64 + d2];
                    const float x1 = acc[mt][p][r] + b1;
                    const float x2 = acc[mt][p + 2][r] + b2;
                    const float y1 = (x1 * c1 - x2 * s1) * qscale;
                    const float y2 = (x2 * c2 + x1 * s2) * qscale;
                    const size_t base = (((size_t)(bb * H_SZ + hh)) * T_SZ + tg) * 64;
                    short h_, l_;
                    split1(y1, &h_, &l_); Hd[base + d1] = h_; Ld[base + d1] = l_;
                    split1(y2, &h_, &l_); Hd[base + d2] = h_; Ld[base + d2] = l_;
                }
            }
    } else {
#pragma unroll
        for (int nt = 0; nt < 4; ++nt) {
            const int d = nt * 16 + l15;
            const float bvv = bias[n0 + wn * 64 + d];
#pragma unroll
            for (int mt = 0; mt < 4; ++mt)
#pragma unroll
                for (int r = 0; r < 4; ++r) {
                    const int m = m0 + wm * 64 + mt * 16 + quad * 4 + r;
                    const int bb = m >> 11, tg = m & (T_SZ - 1);
                    Vb[(((size_t)(bb * H_SZ + hh)) * T_SZ + tg) * 64 + d] =
                        f2bf(acc[mt][nt][r] + bvv);
                }
        }
    }
}

// ---------------------------------------------------------------------------
// Output projection GEMM, same 2-phase double-buffered schedule.
// ---------------------------------------------------------------------------
__global__ __launch_bounds__(256)
void gemm_out_kernel(const short* __restrict__ Ah, const short* __restrict__ Al,
                     const short* __restrict__ Wh, const short* __restrict__ Wl,
                     const float* __restrict__ bias, float* __restrict__ C)
{
    __shared__ __align__(16) short Ahs[2][4096];
    __shared__ __align__(16) short Als[2][4096];
    __shared__ __align__(16) short Whs[2][4096];
    __shared__ __align__(16) short Wls[2][4096];

    const int m0 = blockIdx.x * 128, n0 = blockIdx.y * 128;
    const int tid = threadIdx.x;
    const int wv = tid >> 6, lane = tid & 63;
    const int wm = wv >> 1, wn = wv & 1;
    const int l15 = lane & 15, quad = lane >> 4;

    f32x4 acc[4][4];
#pragma unroll
    for (int mt = 0; mt < 4; ++mt)
#pragma unroll
        for (int nt = 0; nt < 4; ++nt)
            acc[mt][nt] = (f32x4){0.f, 0.f, 0.f, 0.f};

    const size_t aoff = (size_t)(m0 + wv * 32 + (lane >> 2)) * D_SZ + (lane & 3) * 8;
    const size_t woff = (size_t)(n0 + wv * 32 + (lane >> 2)) * D_SZ + (lane & 3) * 8;
    const short* ahg = Ah + aoff;
    const short* alg = Al + aoff;
    const short* whg = Wh + woff;
    const short* wlg = Wl + woff;

#define STAGEO(bi, kk)                                                        \
    do {                                                                      \
        short* a0 = &Ahs[bi][wv * 1024];                                      \
        short* a1 = &Als[bi][wv * 1024];                                      \
        short* w0 = &Whs[bi][wv * 1024];                                      \
        short* w1 = &Wls[bi][wv * 1024];                                      \
        GLDS16(ahg + (kk),             a0);                                   \
        GLDS16(ahg + 16 * D_SZ + (kk), a0 + 512);                             \
        GLDS16(alg + (kk),             a1);                                   \
        GLDS16(alg + 16 * D_SZ + (kk), a1 + 512);                             \
        GLDS16(whg + (kk),             w0);                                   \
        GLDS16(whg + 16 * D_SZ + (kk), w0 + 512);                             \
        GLDS16(wlg + (kk),             w1);                                   \
        GLDS16(wlg + 16 * D_SZ + (kk), w1 + 512);                             \
    } while (0)

    STAGEO(0, 0);
    for (int k0 = 0; k0 < D_SZ; k0 += 32) {
        const int cur = (k0 >> 5) & 1;
        __syncthreads();
        if (k0 + 32 < D_SZ) STAGEO(cur ^ 1, k0 + 32);

        bf16x8 ah[4], al[4];
#pragma unroll
        for (int mt = 0; mt < 4; ++mt) {
            const int arow = (wm * 64 + mt * 16 + l15) * 32 + quad * 8;
            ah[mt] = *(const bf16x8*)&Ahs[cur][arow];
            al[mt] = *(const bf16x8*)&Als[cur][arow];
        }
#pragma unroll
        for (int nt = 0; nt < 4; ++nt) {
            const int brow = (wn * 64 + nt * 16 + l15) * 32 + quad * 8;
            const bf16x8 bh = *(const bf16x8*)&Whs[cur][brow];
            const bf16x8 bl = *(const bf16x8*)&Wls[cur][brow];
#pragma unroll
            for (int mt = 0; mt < 4; ++mt) {
                acc[mt][nt] = MFMA16(ah[mt], bh, acc[mt][nt]);
                acc[mt][nt] = MFMA16(al[mt], bh, acc[mt][nt]);
                acc[mt][nt] = MFMA16(ah[mt], bl, acc[mt][nt]);
            }
        }
    }
#undef STAGEO

#pragma unroll
    for (int nt = 0; nt < 4; ++nt) {
        const int col = n0 + wn * 64 + nt * 16 + l15;
        const float bvv = bias[col];
#pragma unroll
        for (int mt = 0; mt < 4; ++mt)
#pragma unroll
            for (int r = 0; r < 4; ++r) {
                const int m = m0 + wm * 64 + mt * 16 + quad * 4 + r;
                C[(size_t)m * D_SZ + col] = acc[mt][nt][r] + bvv;
            }
    }
}

// ---------------------------------------------------------------------------
// MFMA flash attention (R10-measured config, wall 648.6us). QBLK=64.
// T14 async-STAGE prefetch; conflict-free V transpose; __expf softmax.
// P tiles alias Khs (dead between QK^T and next staging); extra barrier
// before P-write. LDS 27648. VGPR 84 via launch_bounds(256,6) — cliff:
// 84->30% occ, 88->22%. R8: no extra staging pointers (spill cascade).
// Output written pre-split hi/lo bf16 for gemm_out staging.
// ---------------------------------------------------------------------------
__global__ __launch_bounds__(256, 6)
void attn_mfma_kernel(const short* __restrict__ Qhg, const short* __restrict__ Qlg,
                      const short* __restrict__ Khg, const short* __restrict__ Klg,
                      const short* __restrict__ Vg,
                      const unsigned char* __restrict__ mask,
                      const int* __restrict__ flags,
                      short* __restrict__ Oh, short* __restrict__ Ol)
{
    __shared__ __align__(16) short Khs[64 * 72];      // K-hi tile; P alias after QK^T
    __shared__ __align__(16) short Kls[64 * 72];
    __shared__ __align__(16) short Vt[64 * 72];       // [d][t]

    const int bh = blockIdx.y;
    const int b = bh >> 4, h = bh & 15;
    const int q0 = blockIdx.x * 64;
    const int tid = threadIdx.x;
    const int wv = tid >> 6, lane = tid & 63;
    const int l15 = lane & 15, quad = lane >> 4;

    // Q fragments: direct bf16 loads (A-layout: m=l15, k=quad*8+j)
    const short* qhp = Qhg + ((size_t)bh * T_SZ + q0 + wv * 16 + l15) * 64 + quad * 8;
    const short* qlp = Qlg + ((size_t)bh * T_SZ + q0 + wv * 16 + l15) * 64 + quad * 8;
    bf16x8 qh[2], ql[2];
#pragma unroll
    for (int s = 0; s < 2; ++s) {
        qh[s] = *(const bf16x8*)(qhp + 32 * s);
        ql[s] = *(const bf16x8*)(qlp + 32 * s);
    }

    f32x4 accO[4];
#pragma unroll
    for (int nt = 0; nt < 4; ++nt) accO[nt] = (f32x4){0.f, 0.f, 0.f, 0.f};
    float m_i[4], l_i[4];
#pragma unroll
    for (int r = 0; r < 4; ++r) { m_i[r] = -1e30f; l_i[r] = 0.f; }

    const short* khb = Khg + (size_t)bh * T_SZ * 64;
    const short* klb = Klg + (size_t)bh * T_SZ * 64;
    const short* vb  = Vg  + (size_t)bh * T_SZ * 64;
    const unsigned char* mbase = mask + ((size_t)b * T_SZ + q0) * T_SZ;
    const int* frow = flags + ((size_t)b * 32 + blockIdx.x) * 32;

    // Per-thread fixed addressing for K/V staging.
    const short* kgp[4];   // global sources (advance by kt*64)
    short*       kld[4];   // LDS destinations (fixed)
#pragma unroll
    for (int jj = 0; jj < 4; ++jj) {
        const int cc = tid + 256 * (jj & 1);
        const int row = cc >> 3, off = (cc & 7) * 8;
        kgp[jj] = ((jj < 2) ? khb : klb) + (size_t)row * 64 + off;
        kld[jj] = ((jj < 2) ? Khs : Kls) + row * 72 + off;
    }
    const int vt0 = (tid & 15) * 4, vd0 = (tid >> 4) * 4;
    const short* vgp[4];
#pragma unroll
    for (int i = 0; i < 4; ++i)
        vgp[i] = vb + (size_t)(vt0 + i) * 64 + vd0;
    short* pw = &Khs[wv * 16 * 72];                   // P tile aliases Khs

    // staging registers (tile kti+1 in flight during compute of kti)
    bf16x8 kst[4];
    uint2  rv[4];
#pragma unroll
    for (int jj = 0; jj < 4; ++jj) kst[jj] = *(const bf16x8*)(kgp[jj]);
#pragma unroll
    for (int i = 0; i < 4; ++i)    rv[i]   = *(const uint2*)(vgp[i]);

    for (int kti = 0; kti < 32; ++kti) {
        const int kt = kti * 64;
        __syncthreads();   // all waves done with P(=Khs)/Vt of prev iter
        // ---- drain staged K regs -> LDS
#pragma unroll
        for (int jj = 0; jj < 4; ++jj)
            *(bf16x8*)kld[jj] = kst[jj];
        // ---- V: register 4x4 transpose -> Vt[d][t], conflict-free writes
#pragma unroll
        for (int c = 0; c < 4; ++c) {
            const int k = c >> 1;
            const unsigned sel = (c & 1) ? 0x07060302u : 0x05040100u;
            const unsigned lo0 = k ? rv[0].y : rv[0].x;
            const unsigned lo1 = k ? rv[1].y : rv[1].x;
            const unsigned lo2 = k ? rv[2].y : rv[2].x;
            const unsigned lo3 = k ? rv[3].y : rv[3].x;
            uint2 o;
            o.x = __builtin_amdgcn_perm(lo1, lo0, sel);  // (t0.c, t1.c)
            o.y = __builtin_amdgcn_perm(lo3, lo2, sel);  // (t2.c, t3.c)
            *(uint2*)&Vt[(vd0 + c) * 72 + vt0] = o;
        }
        // ---- issue next-tile global loads; latency hides under compute below
        if (kti < 31) {
            const size_t adv = (size_t)(kt + 64) * 64;
#pragma unroll
            for (int jj = 0; jj < 4; ++jj)
                kst[jj] = *(const bf16x8*)(kgp[jj] + adv);
#pragma unroll
            for (int i = 0; i < 4; ++i)
                rv[i] = *(const uint2*)(vgp[i] + adv);
        }
        __syncthreads();

        // ---- S = Q K^T (split bf16, 3 products; scale pre-folded into Q)
        f32x4 accS[4];
        __builtin_amdgcn_s_setprio(1);
#pragma unroll
        for (int nt = 0; nt < 4; ++nt) {
            f32x4 acc = (f32x4){0.f, 0.f, 0.f, 0.f};
#pragma unroll
            for (int s = 0; s < 2; ++s) {
                const bf16x8 kh = *(const bf16x8*)&Khs[(nt * 16 + l15) * 72 + 32 * s + quad * 8];
                const bf16x8 kl = *(const bf16x8*)&Kls[(nt * 16 + l15) * 72 + 32 * s + quad * 8];
                acc = MFMA16(qh[s], kh, acc);
                acc = MFMA16(ql[s], kh, acc);
                acc = MFMA16(qh[s], kl, acc);
            }
            accS[nt] = acc;
        }
        __builtin_amdgcn_s_setprio(0);

        float sv[4][4];   // [nt][r]
        if (frow[kti]) {  // rare masked path
#pragma unroll
            for (int nt = 0; nt < 4; ++nt)
#pragma unroll
                for (int r = 0; r < 4; ++r) {
                    const unsigned char mb =
                        mbase[(size_t)(wv * 16 + quad * 4 + r) * T_SZ + kt + nt * 16 + l15];
                    sv[nt][r] = mb ? -1e30f : accS[nt][r];
                }
        } else {
#pragma unroll
            for (int nt = 0; nt < 4; ++nt)
#pragma unroll
                for (int r = 0; r < 4; ++r)
                    sv[nt][r] = accS[nt][r];
        }

        // ---- online softmax; only the row-max is cross-lane per tile
        float rmax[4];
#pragma unroll
        for (int r = 0; r < 4; ++r)
            rmax[r] = fmaxf(fmaxf(sv[0][r], sv[1][r]), fmaxf(sv[2][r], sv[3][r]));
#pragma unroll
        for (int off = 1; off < 16; off <<= 1)
#pragma unroll
            for (int r = 0; r < 4; ++r)
                rmax[r] = fmaxf(rmax[r], __shfl_xor(rmax[r], off, 64));

        float alpha[4];
#pragma unroll
        for (int r = 0; r < 4; ++r) {
            const float mnew = fmaxf(m_i[r], rmax[r]);
            alpha[r] = __expf(m_i[r] - mnew);
            m_i[r] = mnew;
        }
        float lsum[4] = {0.f, 0.f, 0.f, 0.f};
#pragma unroll
        for (int nt = 0; nt < 4; ++nt)
#pragma unroll
            for (int r = 0; r < 4; ++r) {
                const float p = __expf(sv[nt][r] - m_i[r]);
                sv[nt][r] = p;
                lsum[r] += p;
            }
#pragma unroll
        for (int r = 0; r < 4; ++r)
            l_i[r] = l_i[r] * alpha[r] + lsum[r];   // lane-partial; reduced at end

        // ---- all waves must be past their Khs reads before P overwrites it
        __syncthreads();

        // ---- P -> bf16 (round-half-up) -> per-wave tile in Khs-alias
#pragma unroll
        for (int nt = 0; nt < 4; ++nt)
#pragma unroll
            for (int r = 0; r < 4; ++r) {
                fui u; u.f = sv[nt][r];
                pw[(quad * 4 + r) * 72 + nt * 16 + l15] = (short)((u.u + 0x8000u) >> 16);
            }

        // ---- O = O*alpha + P @ V
#pragma unroll
        for (int nt = 0; nt < 4; ++nt)
#pragma unroll
            for (int r = 0; r < 4; ++r)
                accO[nt][r] *= alpha[r];

        bf16x8 pa[2];
#pragma unroll
        for (int s = 0; s < 2; ++s)
            pa[s] = *(const bf16x8*)&pw[l15 * 72 + 32 * s + quad * 8];
        __builtin_amdgcn_s_setprio(1);
#pragma unroll
        for (int nt = 0; nt < 4; ++nt)
#pragma unroll
            for (int s = 0; s < 2; ++s) {
                const bf16x8 vf = *(const bf16x8*)&Vt[(nt * 16 + l15) * 72 + 32 * s + quad * 8];
                accO[nt] = MFMA16(pa[s], vf, accO[nt]);
            }
        __builtin_amdgcn_s_setprio(0);
    }

    // final cross-lane reduction of l partials (m_i already lane-uniform)
#pragma unroll
    for (int off = 1; off < 16; off <<= 1)
#pragma unroll
        for (int r = 0; r < 4; ++r)
            l_i[r] += __shfl_xor(l_i[r], off, 64);

#pragma unroll
    for (int r = 0; r < 4; ++r) {
        const float inv = 1.f / l_i[r];
        const int t = q0 + wv * 16 + quad * 4 + r;
        const size_t base = ((size_t)(b * T_SZ + t)) * D_SZ + h * DK_SZ;
#pragma unroll
        for (int nt = 0; nt < 4; ++nt) {
            short h_, l_;
            split1(accO[nt][r] * inv, &h_, &l_);
            Oh[base + nt * 16 + l15] = h_;
            Ol[base + nt * 16 + l15] = l_;
        }
    }
}

// ---------------------------------------------------------------------------
extern "C" void kernel_launch(void* const* d_in, const int* in_sizes, int n_in,
                              void* d_out, int out_size, void* d_ws, size_t ws_size,
                              hipStream_t stream)
{
    const float* query = (const float*)d_in[0];
    const float* key   = (const float*)d_in[1];
    const float* value = (const float*)d_in[2];
    const float* cosb  = (const float*)d_in[3];
    const float* sinb  = (const float*)d_in[4];
    const unsigned char* mask = (const unsigned char*)d_in[5];
    const float* Wq = (const float*)d_in[6];
    const float* bq = (const float*)d_in[7];
    const float* Wk = (const float*)d_in[8];
    const float* bk = (const float*)d_in[9];
    const float* Wv = (const float*)d_in[10];
    const float* bv = (const float*)d_in[11];
    const float* Wo = (const float*)d_in[12];
    const float* bo = (const float*)d_in[13];
    float* out = (float*)d_out;

    // workspace layout (shorts): Qh Ql Kh Kl Vb (5*eb, 80MB) |
    // Xh Xl (2*eb, 32MB: A-split during qkv phase, attn-output split after) |
    // 8x weight splits (16MB) | flags (16KB)  -> ~134MB total
    short* sp = (short*)d_ws;
    const size_t eb = (size_t)B_SZ * H_SZ * T_SZ * DK_SZ;   // 8388608 elems
    short* Qh = sp;          short* Ql = sp + eb;
    short* Kh = sp + 2 * eb; short* Kl = sp + 3 * eb;
    short* Vb = sp + 4 * eb;
    short* Xh = sp + 5 * eb; short* Xl = sp + 6 * eb;       // time-shared region
    short* wsp = sp + 7 * eb;
    const size_t wlen = (size_t)D_SZ * D_SZ;
    short* wqh = wsp;            short* wql = wsp + wlen;
    short* wkh = wsp + 2 * wlen; short* wkl = wsp + 3 * wlen;
    short* wvh = wsp + 4 * wlen; short* wvl = wsp + 5 * wlen;
    short* woh = wsp + 6 * wlen; short* wol = wsp + 7 * wlen;
    int* flags = (int*)(wsp + 8 * wlen);

    const int aBlocks = (int)((size_t)M_SZ * D_SZ / 4 / 256);         // 8192
    // fused preprocessing: 4 weight splits + query split + mask flags
    preproc_kernel<<<4096 + 8192 + 1024, 256, 0, stream>>>(
        Wq, Wk, Wv, Wo, query, wqh, wql, Xh, Xl, mask, flags);

    // q / k / v projections; X region serially reused for the A-splits
    qkv_mfma_kernel<<<dim3(M_SZ / 128, 8), 256, 0, stream>>>(
        Xh, Xl, wqh, wql, bq, cosb, sinb, Qh, Ql, Vb, 0);
    wsplit_kernel<<<aBlocks, 256, 0, stream>>>(key, Xh, Xl);
    qkv_mfma_kernel<<<dim3(M_SZ / 128, 8), 256, 0, stream>>>(
        Xh, Xl, wkh, wkl, bk, cosb, sinb, Kh, Kl, Vb, 1);
    wsplit_kernel<<<aBlocks, 256, 0, stream>>>(value, Xh, Xl);
    qkv_mfma_kernel<<<dim3(M_SZ / 128, 8), 256, 0, stream>>>(
        Xh, Xl, wvh, wvl, bv, cosb, sinb, Qh, Ql, Vb, 2);

    // attention writes its output pre-split into the (now free) X region
    attn_mfma_kernel<<<dim3(T_SZ / 64, B_SZ * H_SZ), 256, 0, stream>>>(
        Qh, Ql, Kh, Kl, Vb, mask, flags, Xh, Xl);

    gemm_out_kernel<<<dim3(M_SZ / 128, D_SZ / 128), 256, 0, stream>>>(
        Xh, Xl, woh, wol, bo, out);
}